// Round 10
// baseline (253.330 us; speedup 1.0000x reference)
//
#include <hip/hip_runtime.h>
#include <hip/hip_bf16.h>

typedef _Float16 f16;
typedef _Float16 f16x8 __attribute__((ext_vector_type(8)));
typedef _Float16 f16x4 __attribute__((ext_vector_type(4)));
typedef float f32x4 __attribute__((ext_vector_type(4)));

// ---------------- ws layout (bytes) ----------------
#define P_OFF   0
#define W1T_OFF 14745600
#define W2T_OFF 15007744

// ---------------- k_prop: P build (blocks 0-1023) + weight prep (1024-1215) ----
__global__ __launch_bounds__(256) void k_prop(const float* __restrict__ graph,
                                              float* __restrict__ P,
                                              const float* __restrict__ W1,
                                              const float* __restrict__ W2,
                                              f16* __restrict__ w1t,
                                              f16* __restrict__ w2t) {
    __shared__ float MtS[4][990];
    __shared__ float dinvS[4][32];
    __shared__ f16 qhS[4][1024];
    __shared__ f16 qlS[4][1024];

    if (blockIdx.x >= 1024) {   // ---- weight transpose+cvt path ----
        long base = ((long)(blockIdx.x - 1024) * 256 + threadIdx.x) * 8;
        #pragma unroll
        for (int j = 0; j < 8; ++j) {
            long id = base + j;
            if (id < 131072) {
                int f = (int)(id >> 8), k = (int)(id & 255);
                w1t[id] = (f16)W1[k * 512 + f];               // w1t[f][k]
            } else {
                long i = id - 131072;
                int f = (int)(i >> 9), k = (int)(i & 511);
                w2t[i] = (f16)W2[k * 512 + f];                // w2t[f][k]
            }
        }
        return;
    }

    const int wv = threadIdx.x >> 6, lane = threadIdx.x & 63;
    const int lr = lane & 15, gq = lane >> 4;
    const long b = (long)blockIdx.x * 4 + wv;
    const float* g = graph + b * 4500;
    float* Mt = MtS[wv];
    float* dinv = dinvS[wv];
    f16* qh = qhS[wv];
    f16* ql = qlS[wv];

    for (int rep = 0; rep < 15; ++rep) {
        int e = rep * 64 + lane;
        if (e < 900) {
            float s = g[e] + g[900 + e] + g[1800 + e] + g[2700 + e] + g[3600 + e];
            int r = e / 30, c = e - r * 30;
            Mt[r * 33 + c] = ((s != 0.f) ? 1.f : 0.f) + ((r == c) ? 1.f : 0.f);
        }
    }
    __syncthreads();
    if (lane < 30) {
        float d = 0.f;
        #pragma unroll
        for (int r = 0; r < 30; ++r) d += Mt[r * 33 + lane];
        dinv[lane] = 1.0f / sqrtf(d);
    }
    __syncthreads();

    auto Sval = [&](int i, int j) -> float {
        if (i >= 30 || j >= 30) return 0.f;
        return dinv[i] * Mt[j * 33 + i] * dinv[j];
    };

    f16x8 sh[2], sl[2];
    #pragma unroll
    for (int mi = 0; mi < 2; ++mi)
        #pragma unroll
        for (int jj = 0; jj < 8; ++jj) {
            float v = Sval(mi * 16 + lr, gq * 8 + jj);
            f16 h = (f16)v;
            sh[mi][jj] = h;
            sl[mi][jj] = (f16)(v - (float)h);
        }

    f32x4 qd[2][2], racc[2][2];
    #pragma unroll
    for (int mi = 0; mi < 2; ++mi)
        #pragma unroll
        for (int ni = 0; ni < 2; ++ni)
            #pragma unroll
            for (int r = 0; r < 4; ++r) {
                int row = mi * 16 + gq * 4 + r, col = ni * 16 + lr;
                qd[mi][ni][r] = Sval(row, col);
                racc[mi][ni][r] = (row == col) ? 0.1f : 0.f;
            }

    float c = 0.1f;
    for (int k = 1; k <= 9; ++k) {
        c *= 0.9f;
        #pragma unroll
        for (int mi = 0; mi < 2; ++mi)
            #pragma unroll
            for (int ni = 0; ni < 2; ++ni) {
                racc[mi][ni] += c * qd[mi][ni];
                f16x4 hh, ll;
                #pragma unroll
                for (int r = 0; r < 4; ++r) {
                    float v = qd[mi][ni][r];
                    f16 h = (f16)v;
                    hh[r] = h;
                    ll[r] = (f16)(v - (float)h);
                }
                const int col = ni * 16 + lr, rowb = mi * 16 + gq * 4;
                *reinterpret_cast<f16x4*>(qh + col * 32 + rowb) = hh;
                *reinterpret_cast<f16x4*>(ql + col * 32 + rowb) = ll;
            }
        __syncthreads();
        f16x8 bh[2], bl[2];
        #pragma unroll
        for (int ni = 0; ni < 2; ++ni) {
            const int col = ni * 16 + lr;
            bh[ni] = *reinterpret_cast<const f16x8*>(qh + col * 32 + gq * 8);
            bl[ni] = *reinterpret_cast<const f16x8*>(ql + col * 32 + gq * 8);
        }
        #pragma unroll
        for (int mi = 0; mi < 2; ++mi)
            #pragma unroll
            for (int ni = 0; ni < 2; ++ni) {
                f32x4 d = {0.f, 0.f, 0.f, 0.f};
                d = __builtin_amdgcn_mfma_f32_16x16x32_f16(sh[mi], bh[ni], d, 0, 0, 0);
                d = __builtin_amdgcn_mfma_f32_16x16x32_f16(sh[mi], bl[ni], d, 0, 0, 0);
                d = __builtin_amdgcn_mfma_f32_16x16x32_f16(sl[mi], bh[ni], d, 0, 0, 0);
                qd[mi][ni] = d;
            }
        __syncthreads();
    }
    const float cf = 0.3486784401f;   // 0.9^10
    #pragma unroll
    for (int mi = 0; mi < 2; ++mi)
        #pragma unroll
        for (int ni = 0; ni < 2; ++ni)
            #pragma unroll
            for (int r = 0; r < 4; ++r) {
                int row = mi * 16 + gq * 4 + r, col = ni * 16 + lr;
                if (row < 30 && col < 30)
                    P[b * 900 + row * 30 + col] = racc[mi][ni][r] + cf * qd[mi][ni][r];
            }
}

// ---------------- k_main ----------------
// block = 2 batches (rows 0-29, 32-61 valid; 30,31,62,63 zero), M=64.
// 256 threads = 4 waves; wave owns 128 feature-cols. 2 blocks/CU (LDS 78.3K).
// buf alias: As[64][256] f16 (32K) -> xl[64][512] f16 (64K) -> ut[512][64] f16 (64K)
#define SMEM_BYTES 78336
#define PF_OFF   65536   // Pf [2][32][40] f16 = 5120
#define B1L_OFF  70656   // [512] f32
#define B2L_OFF  72704   // [512] f32
#define WLL_OFF  74752   // [512] f32
#define RED_OFF  76800   // [4][64] f32 = 1024
#define VL_OFF   77824   // [64] f32
#define ZL_OFF   78080   // [64] f32

__global__ __launch_bounds__(256, 2) void k_main(
    const float* __restrict__ real, const f16* __restrict__ w1t,
    const f16* __restrict__ w2t, const float* __restrict__ b1,
    const float* __restrict__ b2, const float* __restrict__ wl,
    const float* __restrict__ bl, const float* __restrict__ wc,
    const float* __restrict__ bc, const float* __restrict__ Pws,
    float* __restrict__ out) {
    extern __shared__ char smem[];
    char*  buf = smem;
    f16*   Pf  = (f16*)(smem + PF_OFF);
    float* b1l = (float*)(smem + B1L_OFF);
    float* b2l = (float*)(smem + B2L_OFF);
    float* wll = (float*)(smem + WLL_OFF);
    float* red = (float*)(smem + RED_OFF);
    float* vl  = (float*)(smem + VL_OFF);
    float* zl  = (float*)(smem + ZL_OFF);

    const int tid  = threadIdx.x;
    const int lane = tid & 63;
    const int wv   = tid >> 6;           // 0..3, owns feats wv*128..+127
    const int gq   = lane >> 4;
    const int lr   = lane & 15;
    const int blk  = blockIdx.x;         // 0..2047
    const long r0  = (long)blk * 60;

    // ---- stage As[64][256] f16, rows 512B, swizzle (row&7)<<4; pads zero ----
    {
        const int srow = tid >> 2;                  // 0..63
        const int seg  = tid & 3;                   // 64-float segment
        const int rr   = srow & 31;
        const bool valid = rr < 30;
        const float* p = real + (r0 + (long)(srow >> 5) * 30 + rr) * 256 + seg * 64;
        #pragma unroll
        for (int q = 0; q < 8; ++q) {
            f32x4 v0 = {0.f,0.f,0.f,0.f}, v1 = {0.f,0.f,0.f,0.f};
            if (valid) {
                v0 = *reinterpret_cast<const f32x4*>(p + q * 8);
                v1 = *reinterpret_cast<const f32x4*>(p + q * 8 + 4);
            }
            f16x8 h;
            h[0]=(f16)v0[0]; h[1]=(f16)v0[1]; h[2]=(f16)v0[2]; h[3]=(f16)v0[3];
            h[4]=(f16)v1[0]; h[5]=(f16)v1[1]; h[6]=(f16)v1[2]; h[7]=(f16)v1[3];
            *reinterpret_cast<f16x8*>(
                buf + srow * 512 + ((seg * 128 + q * 16) ^ ((srow & 7) << 4))) = h;
        }
    }
    // ---- Pf [2][32][40] f16 (zero-padded) ----
    #pragma unroll
    for (int s = 0; s < 8; ++s) {
        int e = tid + s * 256;            // 0..2047
        int bb = e >> 10, idx = e & 1023, n = idx >> 5, kk = idx & 31;
        float p = (n < 30 && kk < 30)
            ? Pws[((long)blk * 2 + bb) * 900 + n * 30 + kk] : 0.f;
        Pf[bb * 1280 + n * 40 + kk] = (f16)p;
    }
    b1l[tid] = b1[tid];         b1l[tid + 256] = b1[tid + 256];
    b2l[tid] = b2[tid];         b2l[tid + 256] = b2[tid + 256];
    wll[tid] = wl[tid];         wll[tid + 256] = wl[tid + 256];

    f32x4 acc[8][4];
    #pragma unroll
    for (int a = 0; a < 8; ++a)
        #pragma unroll
        for (int b = 0; b < 4; ++b) { f32x4 z = {0.f,0.f,0.f,0.f}; acc[a][b] = z; }
    __syncthreads();

    // ======== GEMM1: D[feat][node] = W1^T @ A^T, K=256 — barrier-free ========
    const f16* w1p = w1t + (wv * 128 + lr) * 256;
    {
        f16x8 waA[8], waB[8];
        #pragma unroll
        for (int mi = 0; mi < 8; ++mi) {
            waA[mi] = *reinterpret_cast<const f16x8*>(w1p + mi * 4096 + gq * 8);
            waB[mi] = *reinterpret_cast<const f16x8*>(w1p + mi * 4096 + 32 + gq * 8);
        }
        #pragma unroll
        for (int kc2 = 0; kc2 < 4; ++kc2) {
            #pragma unroll
            for (int half = 0; half < 2; ++half) {
                const int kc = 2 * kc2 + half;
                f16x8 bf[4];
                #pragma unroll
                for (int ni = 0; ni < 4; ++ni) {
                    const int row = ni * 16 + lr;
                    bf[ni] = *reinterpret_cast<const f16x8*>(
                        buf + row * 512 + ((kc * 64 + gq * 16) ^ ((row & 7) << 4)));
                }
                __builtin_amdgcn_s_setprio(1);
                #pragma unroll
                for (int mi = 0; mi < 8; ++mi)
                    #pragma unroll
                    for (int ni = 0; ni < 4; ++ni)
                        acc[mi][ni] = __builtin_amdgcn_mfma_f32_16x16x32_f16(
                            half ? waB[mi] : waA[mi], bf[ni], acc[mi][ni], 0, 0, 0);
                __builtin_amdgcn_s_setprio(0);
                if (kc + 2 < 8) {
                    #pragma unroll
                    for (int mi = 0; mi < 8; ++mi) {
                        f16x8 w = *reinterpret_cast<const f16x8*>(
                            w1p + mi * 4096 + (kc + 2) * 32 + gq * 8);
                        if (half) waB[mi] = w; else waA[mi] = w;
                    }
                }
            }
        }
    }
    __syncthreads();   // As reads done; buf -> xl[64][512] f16

    // ---- ep1: xl[node][feat] = relu(acc + b1), b64 writes, (node&15)<<4 swz ----
    #pragma unroll
    for (int mi = 0; mi < 8; ++mi) {
        const int featb = wv * 128 + mi * 16 + gq * 4;
        float b1v[4];
        #pragma unroll
        for (int j = 0; j < 4; ++j) b1v[j] = b1l[featb + j];
        #pragma unroll
        for (int ni = 0; ni < 4; ++ni) {
            const int node = ni * 16 + lr;
            f16x4 h;
            #pragma unroll
            for (int j = 0; j < 4; ++j)
                h[j] = (f16)fmaxf(acc[mi][ni][j] + b1v[j], 0.f);
            *reinterpret_cast<f16x4*>(
                buf + node * 1024 + ((featb * 2) ^ ((node & 15) << 4))) = h;
        }
    }
    #pragma unroll
    for (int a = 0; a < 8; ++a)
        #pragma unroll
        for (int b = 0; b < 4; ++b) { f32x4 z = {0.f,0.f,0.f,0.f}; acc[a][b] = z; }
    __syncthreads();

    // ======== GEMM2: D[node][feat] = x @ W2, K=512 — barrier-free ========
    const f16* w2p = w2t + (wv * 128 + lr) * 512;
    {
        f16x8 bwA[8], bwB[8];
        #pragma unroll
        for (int fi = 0; fi < 8; ++fi) {
            bwA[fi] = *reinterpret_cast<const f16x8*>(w2p + fi * 8192 + gq * 8);
            bwB[fi] = *reinterpret_cast<const f16x8*>(w2p + fi * 8192 + 32 + gq * 8);
        }
        #pragma unroll
        for (int kc2 = 0; kc2 < 8; ++kc2) {
            #pragma unroll
            for (int half = 0; half < 2; ++half) {
                const int kc = 2 * kc2 + half;
                f16x8 af[4];
                #pragma unroll
                for (int nj = 0; nj < 4; ++nj) {
                    const int row = nj * 16 + lr;
                    af[nj] = *reinterpret_cast<const f16x8*>(
                        buf + row * 1024 + (((kc * 32 + gq * 8) * 2) ^ ((row & 15) << 4)));
                }
                __builtin_amdgcn_s_setprio(1);
                #pragma unroll
                for (int fi = 0; fi < 8; ++fi)
                    #pragma unroll
                    for (int nj = 0; nj < 4; ++nj)
                        acc[fi][nj] = __builtin_amdgcn_mfma_f32_16x16x32_f16(
                            af[nj], half ? bwB[fi] : bwA[fi], acc[fi][nj], 0, 0, 0);
                __builtin_amdgcn_s_setprio(0);
                if (kc + 2 < 16) {
                    #pragma unroll
                    for (int fi = 0; fi < 8; ++fi) {
                        f16x8 w = *reinterpret_cast<const f16x8*>(
                            w2p + fi * 8192 + (kc + 2) * 32 + gq * 8);
                        if (half) bwB[fi] = w; else bwA[fi] = w;
                    }
                }
            }
        }
    }
    __syncthreads();   // xl reads done; buf -> ut[512][64]

    // ---- ep2: ut[feat][node], b64 writes, 128B rows, (feat&7)<<4 swizzle ----
    #pragma unroll
    for (int fi = 0; fi < 8; ++fi)
        #pragma unroll
        for (int nj = 0; nj < 4; ++nj) {
            const int feat  = wv * 128 + fi * 16 + lr;
            const int node0 = nj * 16 + gq * 4;
            f16x4 h;
            #pragma unroll
            for (int j = 0; j < 4; ++j) h[j] = (f16)acc[fi][nj][j];
            *reinterpret_cast<f16x4*>(
                buf + feat * 128 + ((node0 * 2) ^ ((feat & 7) << 4))) = h;
        }
    __syncthreads();

    // ======== phase5: Y^T = U^T @ P^T (per batch), y=relu(+b2), v=y.wl ========
    {
        f16x8 pb[2][2];
        #pragma unroll
        for (int bb = 0; bb < 2; ++bb)
            #pragma unroll
            for (int ni = 0; ni < 2; ++ni)
                pb[bb][ni] = *reinterpret_cast<const f16x8*>(
                    Pf + bb * 1280 + (ni * 16 + lr) * 40 + gq * 8);
        float vacc[2][2];
        #pragma unroll
        for (int bb = 0; bb < 2; ++bb)
            #pragma unroll
            for (int ni = 0; ni < 2; ++ni) vacc[bb][ni] = 0.f;
        #pragma unroll
        for (int mi = 0; mi < 8; ++mi) {
            const int featb = wv * 128 + mi * 16;
            float b2v[4], wlv[4];
            #pragma unroll
            for (int j = 0; j < 4; ++j) {
                b2v[j] = b2l[featb + gq * 4 + j];
                wlv[j] = wll[featb + gq * 4 + j];
            }
            f16x8 au[2];
            #pragma unroll
            for (int bb = 0; bb < 2; ++bb) {
                const int feat = featb + lr;
                au[bb] = *reinterpret_cast<const f16x8*>(
                    buf + feat * 128 + ((bb * 64 + gq * 16) ^ ((feat & 7) << 4)));
            }
            #pragma unroll
            for (int bb = 0; bb < 2; ++bb)
                #pragma unroll
                for (int ni = 0; ni < 2; ++ni) {
                    f32x4 d = {0.f,0.f,0.f,0.f};
                    d = __builtin_amdgcn_mfma_f32_16x16x32_f16(au[bb], pb[bb][ni], d, 0, 0, 0);
                    #pragma unroll
                    for (int j = 0; j < 4; ++j) {
                        float y = fmaxf(d[j] + b2v[j], 0.f);
                        vacc[bb][ni] = fmaf(y, wlv[j], vacc[bb][ni]);
                    }
                }
        }
        #pragma unroll
        for (int bb = 0; bb < 2; ++bb)
            #pragma unroll
            for (int ni = 0; ni < 2; ++ni) {
                float v = vacc[bb][ni];
                v += __shfl_xor(v, 16);
                v += __shfl_xor(v, 32);
                if (lane < 16) red[wv * 64 + bb * 32 + ni * 16 + lr] = v;
            }
    }
    __syncthreads();
    if (tid < 64) {
        float s = 0.f;
        #pragma unroll
        for (int w = 0; w < 4; ++w) s += red[w * 64 + tid];
        vl[tid] = s;
    }
    __syncthreads();
    if (tid < 60) {
        const int bb = tid / 30, n = tid - bb * 30;
        const float* Pr = Pws + ((long)blk * 2 + bb) * 900 + n * 30;
        float z = bl[0];
        #pragma unroll
        for (int j = 0; j < 30; ++j) z = fmaf(Pr[j], vl[bb * 32 + j], z);
        zl[tid] = fmaxf(z, 0.f);
    }
    __syncthreads();
    if (tid < 8) {
        const int bb = tid >> 2, cc = tid & 3;
        float o = bc[cc];
        #pragma unroll
        for (int n = 0; n < 30; ++n) o = fmaf(zl[bb * 30 + n], wc[cc * 30 + n], o);
        out[((long)blk * 2 + bb) * 4 + cc] = o;
    }
}

extern "C" void kernel_launch(void* const* d_in, const int* in_sizes, int n_in,
                              void* d_out, int out_size, void* d_ws, size_t ws_size,
                              hipStream_t stream) {
    const float* real  = (const float*)d_in[0];
    const float* graph = (const float*)d_in[2];
    const float* W1    = (const float*)d_in[3];
    const float* b1    = (const float*)d_in[4];
    const float* W2    = (const float*)d_in[5];
    const float* b2    = (const float*)d_in[6];
    const float* Wl    = (const float*)d_in[7];
    const float* bl    = (const float*)d_in[8];
    const float* Wc    = (const float*)d_in[9];
    const float* bc    = (const float*)d_in[10];
    float* out = (float*)d_out;
    char*  ws  = (char*)d_ws;

    float* Pws = (float*)(ws + P_OFF);
    f16*   w1t = (f16*)(ws + W1T_OFF);
    f16*   w2t = (f16*)(ws + W2T_OFF);

    k_prop<<<1216, 256, 0, stream>>>(graph, Pws, W1, W2, w1t, w2t);
    (void)hipFuncSetAttribute((const void*)k_main,
                              hipFuncAttributeMaxDynamicSharedMemorySize, SMEM_BYTES);
    k_main<<<2048, 256, SMEM_BYTES, stream>>>(real, w1t, w2t, b1, b2, Wl, bl, Wc, bc,
                                              Pws, out);
}

// Round 11
// 172.424 us; speedup vs baseline: 1.4692x; 1.4692x over previous
//
#include <hip/hip_runtime.h>
#include <hip/hip_bf16.h>

typedef _Float16 f16;
typedef _Float16 f16x8 __attribute__((ext_vector_type(8)));
typedef _Float16 f16x4 __attribute__((ext_vector_type(4)));
typedef float f32x4 __attribute__((ext_vector_type(4)));

#define LGKM_FENCE() do { \
    asm volatile("s_waitcnt lgkmcnt(0)" ::: "memory"); \
    __builtin_amdgcn_sched_barrier(0); \
} while (0)

// ---------------- ws layout (bytes) ----------------
#define P_OFF   0
#define W1T_OFF 14745600
#define W2T_OFF 15007744

// ---------------- k_prep: transpose + f32->f16 weights ----------------
__global__ __launch_bounds__(256) void k_prep(const float* __restrict__ W1,
                                              const float* __restrict__ W2,
                                              f16* __restrict__ w1t,
                                              f16* __restrict__ w2t) {
    long base = ((long)blockIdx.x * 256 + threadIdx.x) * 8;
    #pragma unroll
    for (int j = 0; j < 8; ++j) {
        long id = base + j;
        if (id < 131072) {
            int f = (int)(id >> 8), k = (int)(id & 255);
            w1t[id] = (f16)W1[k * 512 + f];               // w1t[f][k]
        } else {
            long i = id - 131072;
            int f = (int)(i >> 9), k = (int)(i & 511);
            w2t[i] = (f16)W2[k * 512 + f];                // w2t[f][k]
        }
    }
}

// ---------------- k_main ----------------
// block = 4 batches (rows q*32+0..29 valid, q*32+{30,31} zeroed), M=128.
// 512 threads = 8 waves; wave owns 64 feature-cols.
// Staging fork: waves 0-3 build P (one batch each, intra-wave, fence-ordered);
// waves 4-7 stage As[128][256] f16. Then R9's proven main path.
// buf alias: As 64K | P-scratch 64K..96K -> xl[128][512] 128K -> ut[512][128] 128K
#define SMEM_BYTES 152576
#define PF_OFF   131072  // Pf [4][32][40] f16 = 10240
#define B1L_OFF  141312  // [512] f32
#define B2L_OFF  143360  // [512] f32
#define WLL_OFF  145408  // [512] f32
#define RED_OFF  147456  // [8][128] f32 = 4096
#define VL_OFF   151552  // [128] f32
#define ZL_OFF   152064  // [128] f32

__global__ __launch_bounds__(512, 2) void k_main(
    const float* __restrict__ real, const f16* __restrict__ w1t,
    const f16* __restrict__ w2t, const float* __restrict__ b1,
    const float* __restrict__ b2, const float* __restrict__ wl,
    const float* __restrict__ bl, const float* __restrict__ wc,
    const float* __restrict__ bc, const float* __restrict__ graph,
    float* __restrict__ Pws, float* __restrict__ out) {
    extern __shared__ char smem[];
    char*  buf = smem;
    f16*   Pf  = (f16*)(smem + PF_OFF);
    float* b1l = (float*)(smem + B1L_OFF);
    float* b2l = (float*)(smem + B2L_OFF);
    float* wll = (float*)(smem + WLL_OFF);
    float* red = (float*)(smem + RED_OFF);
    float* vl  = (float*)(smem + VL_OFF);
    float* zl  = (float*)(smem + ZL_OFF);

    const int tid  = threadIdx.x;
    const int lane = tid & 63;
    const int wv   = tid >> 6;
    const int gq   = lane >> 4;
    const int lr   = lane & 15;
    const int blk  = blockIdx.x;         // 0..1023
    const long r0  = (long)blk * 120;

    b1l[tid] = b1[tid];
    b2l[tid] = b2[tid];
    wll[tid] = wl[tid];

    if (wv >= 4) {
        // ---- waves 4-7: stage As[128][256] f16, 512B rows, (row&7)<<4 swz ----
        const int t    = tid & 255;                 // 0..255
        const int srow = t >> 1;                    // 0..127
        const int half = t & 1;                     // which 128-float half
        const int rr   = srow & 31;
        const bool valid = rr < 30;
        const float* p = real + (r0 + (long)(srow >> 5) * 30 + rr) * 256 + half * 128;
        #pragma unroll
        for (int q = 0; q < 16; ++q) {
            f32x4 v0 = {0.f,0.f,0.f,0.f}, v1 = {0.f,0.f,0.f,0.f};
            if (valid) {
                v0 = *reinterpret_cast<const f32x4*>(p + q * 8);
                v1 = *reinterpret_cast<const f32x4*>(p + q * 8 + 4);
            }
            f16x8 h;
            h[0]=(f16)v0[0]; h[1]=(f16)v0[1]; h[2]=(f16)v0[2]; h[3]=(f16)v0[3];
            h[4]=(f16)v1[0]; h[5]=(f16)v1[1]; h[6]=(f16)v1[2]; h[7]=(f16)v1[3];
            *reinterpret_cast<f16x8*>(
                buf + srow * 512 + ((half * 256 + q * 16) ^ ((srow & 7) << 4))) = h;
        }
    } else {
        // ---- waves 0-3: build P for batch blk*4+wv (intra-wave, fences) ----
        char*  sc   = buf + 65536 + wv * 8192;      // 8KB scratch per wave
        float* Mt   = (float*)sc;                   // [30][33] padded
        float* dinv = (float*)(sc + 3968);          // [32]
        f16*   qh   = (f16*)(sc + 4096);            // [32][32] col-major
        f16*   ql   = (f16*)(sc + 6144);
        const long b = (long)blk * 4 + wv;
        const float* g = graph + b * 4500;

        #pragma unroll
        for (int rep = 0; rep < 15; ++rep) {
            int e = rep * 64 + lane;
            if (e < 900) {
                float s = g[e] + g[900 + e] + g[1800 + e] + g[2700 + e] + g[3600 + e];
                int r = e / 30, c = e - r * 30;
                Mt[r * 33 + c] = ((s != 0.f) ? 1.f : 0.f) + ((r == c) ? 1.f : 0.f);
            }
        }
        LGKM_FENCE();
        if (lane < 30) {
            float d = 0.f;
            #pragma unroll
            for (int r = 0; r < 30; ++r) d += Mt[r * 33 + lane];
            dinv[lane] = 1.0f / sqrtf(d);
        }
        LGKM_FENCE();

        auto Sval = [&](int i, int j) -> float {
            if (i >= 30 || j >= 30) return 0.f;
            return dinv[i] * Mt[j * 33 + i] * dinv[j];
        };

        f16x8 sh[2], sl[2];
        #pragma unroll
        for (int mi = 0; mi < 2; ++mi)
            #pragma unroll
            for (int jj = 0; jj < 8; ++jj) {
                float v = Sval(mi * 16 + lr, gq * 8 + jj);
                f16 h = (f16)v;
                sh[mi][jj] = h;
                sl[mi][jj] = (f16)(v - (float)h);
            }

        f32x4 qd[2][2], racc[2][2];
        #pragma unroll
        for (int mi = 0; mi < 2; ++mi)
            #pragma unroll
            for (int ni = 0; ni < 2; ++ni)
                #pragma unroll
                for (int r = 0; r < 4; ++r) {
                    int row = mi * 16 + gq * 4 + r, col = ni * 16 + lr;
                    qd[mi][ni][r] = Sval(row, col);
                    racc[mi][ni][r] = (row == col) ? 0.1f : 0.f;
                }

        float c = 0.1f;
        for (int k = 1; k <= 9; ++k) {
            c *= 0.9f;
            #pragma unroll
            for (int mi = 0; mi < 2; ++mi)
                #pragma unroll
                for (int ni = 0; ni < 2; ++ni) {
                    racc[mi][ni] += c * qd[mi][ni];
                    f16x4 hh, ll;
                    #pragma unroll
                    for (int r = 0; r < 4; ++r) {
                        float v = qd[mi][ni][r];
                        f16 h = (f16)v;
                        hh[r] = h;
                        ll[r] = (f16)(v - (float)h);
                    }
                    const int col = ni * 16 + lr, rowb = mi * 16 + gq * 4;
                    *reinterpret_cast<f16x4*>(qh + col * 32 + rowb) = hh;
                    *reinterpret_cast<f16x4*>(ql + col * 32 + rowb) = ll;
                }
            LGKM_FENCE();
            f16x8 bh[2], bl2[2];
            #pragma unroll
            for (int ni = 0; ni < 2; ++ni) {
                const int col = ni * 16 + lr;
                bh[ni]  = *reinterpret_cast<const f16x8*>(qh + col * 32 + gq * 8);
                bl2[ni] = *reinterpret_cast<const f16x8*>(ql + col * 32 + gq * 8);
            }
            #pragma unroll
            for (int mi = 0; mi < 2; ++mi)
                #pragma unroll
                for (int ni = 0; ni < 2; ++ni) {
                    f32x4 d = {0.f, 0.f, 0.f, 0.f};
                    d = __builtin_amdgcn_mfma_f32_16x16x32_f16(sh[mi], bh[ni],  d, 0, 0, 0);
                    d = __builtin_amdgcn_mfma_f32_16x16x32_f16(sh[mi], bl2[ni], d, 0, 0, 0);
                    d = __builtin_amdgcn_mfma_f32_16x16x32_f16(sl[mi], bh[ni],  d, 0, 0, 0);
                    qd[mi][ni] = d;
                }
        }
        const float cf = 0.3486784401f;   // 0.9^10
        #pragma unroll
        for (int mi = 0; mi < 2; ++mi)
            #pragma unroll
            for (int ni = 0; ni < 2; ++ni)
                #pragma unroll
                for (int r = 0; r < 4; ++r) {
                    int row = mi * 16 + gq * 4 + r, col = ni * 16 + lr;
                    float val = racc[mi][ni][r] + cf * qd[mi][ni][r];
                    bool in = (row < 30 && col < 30);
                    // Pf f16 (zero-padded 32x32, row stride 40)
                    Pf[wv * 1280 + row * 40 + col] = (f16)(in ? val : 0.f);
                    // Pws f32 for the tail (L2-hot by then)
                    if (in) Pws[b * 900 + row * 30 + col] = val;
                }
    }

    f32x4 acc[4][8];
    #pragma unroll
    for (int a = 0; a < 4; ++a)
        #pragma unroll
        for (int b = 0; b < 8; ++b) { f32x4 z = {0.f,0.f,0.f,0.f}; acc[a][b] = z; }
    __syncthreads();                      // As + Pf visible; Pws drained (vmcnt)

    // ======== GEMM1: D[feat][node] = W1^T @ A^T, K=256 — barrier-free ========
    const f16* w1p = w1t + (wv * 64 + lr) * 256;
    {
        f16x8 waA[4], waB[4];
        #pragma unroll
        for (int mi = 0; mi < 4; ++mi) {
            waA[mi] = *reinterpret_cast<const f16x8*>(w1p + mi * 4096 + gq * 8);
            waB[mi] = *reinterpret_cast<const f16x8*>(w1p + mi * 4096 + 32 + gq * 8);
        }
        #pragma unroll
        for (int kc2 = 0; kc2 < 4; ++kc2) {
            #pragma unroll
            for (int half = 0; half < 2; ++half) {
                const int kc = 2 * kc2 + half;
                f16x8 bf[8];
                #pragma unroll
                for (int ni = 0; ni < 8; ++ni) {
                    const int row = ni * 16 + lr;
                    bf[ni] = *reinterpret_cast<const f16x8*>(
                        buf + row * 512 + ((kc * 64 + gq * 16) ^ ((row & 7) << 4)));
                }
                __builtin_amdgcn_s_setprio(1);
                #pragma unroll
                for (int mi = 0; mi < 4; ++mi)
                    #pragma unroll
                    for (int ni = 0; ni < 8; ++ni)
                        acc[mi][ni] = __builtin_amdgcn_mfma_f32_16x16x32_f16(
                            half ? waB[mi] : waA[mi], bf[ni], acc[mi][ni], 0, 0, 0);
                __builtin_amdgcn_s_setprio(0);
                if (kc + 2 < 8) {
                    #pragma unroll
                    for (int mi = 0; mi < 4; ++mi) {
                        f16x8 w = *reinterpret_cast<const f16x8*>(
                            w1p + mi * 4096 + (kc + 2) * 32 + gq * 8);
                        if (half) waB[mi] = w; else waA[mi] = w;
                    }
                }
            }
        }
    }
    __syncthreads();   // As reads done; buf -> xl[128][512] f16

    // ---- ep1: xl[node][feat] = relu(acc + b1), b64 writes, (node&15)<<4 swz ----
    #pragma unroll
    for (int mi = 0; mi < 4; ++mi) {
        const int featb = wv * 64 + mi * 16 + gq * 4;
        float b1v[4];
        #pragma unroll
        for (int j = 0; j < 4; ++j) b1v[j] = b1l[featb + j];
        #pragma unroll
        for (int ni = 0; ni < 8; ++ni) {
            const int node = ni * 16 + lr;
            f16x4 h;
            #pragma unroll
            for (int j = 0; j < 4; ++j)
                h[j] = (f16)fmaxf(acc[mi][ni][j] + b1v[j], 0.f);
            *reinterpret_cast<f16x4*>(
                buf + node * 1024 + ((featb * 2) ^ ((node & 15) << 4))) = h;
        }
    }
    #pragma unroll
    for (int a = 0; a < 4; ++a)
        #pragma unroll
        for (int b = 0; b < 8; ++b) { f32x4 z = {0.f,0.f,0.f,0.f}; acc[a][b] = z; }
    __syncthreads();

    // ======== GEMM2: D[node][feat] = x @ W2, K=512 — barrier-free ========
    const f16* w2p = w2t + (wv * 64 + lr) * 512;
    {
        f16x8 bfA[4], bfB[4];
        #pragma unroll
        for (int ni = 0; ni < 4; ++ni) {
            bfA[ni] = *reinterpret_cast<const f16x8*>(w2p + ni * 8192 + gq * 8);
            bfB[ni] = *reinterpret_cast<const f16x8*>(w2p + ni * 8192 + 32 + gq * 8);
        }
        #pragma unroll
        for (int kc2 = 0; kc2 < 8; ++kc2) {
            #pragma unroll
            for (int half = 0; half < 2; ++half) {
                const int kc = 2 * kc2 + half;
                f16x8 af[8];
                #pragma unroll
                for (int mi = 0; mi < 8; ++mi) {
                    const int row = mi * 16 + lr;
                    af[mi] = *reinterpret_cast<const f16x8*>(
                        buf + row * 1024 + (((kc * 32 + gq * 8) * 2) ^ ((row & 15) << 4)));
                }
                __builtin_amdgcn_s_setprio(1);
                #pragma unroll
                for (int mi = 0; mi < 8; ++mi)
                    #pragma unroll
                    for (int ni = 0; ni < 4; ++ni)
                        acc[ni][mi] = __builtin_amdgcn_mfma_f32_16x16x32_f16(
                            af[mi], half ? bfB[ni] : bfA[ni], acc[ni][mi], 0, 0, 0);
                __builtin_amdgcn_s_setprio(0);
                if (kc + 2 < 16) {
                    #pragma unroll
                    for (int ni = 0; ni < 4; ++ni) {
                        f16x8 w = *reinterpret_cast<const f16x8*>(
                            w2p + ni * 8192 + (kc + 2) * 32 + gq * 8);
                        if (half) bfB[ni] = w; else bfA[ni] = w;
                    }
                }
            }
        }
    }
    __syncthreads();   // xl reads done; buf -> ut[512][128]

    // ---- ep2: ut[feat][node], b64 writes, (feat&15)<<4 swizzle ----
    #pragma unroll
    for (int mi = 0; mi < 8; ++mi)
        #pragma unroll
        for (int ni = 0; ni < 4; ++ni) {
            const int feat  = wv * 64 + ni * 16 + lr;
            const int node0 = mi * 16 + gq * 4;
            f16x4 h;
            #pragma unroll
            for (int j = 0; j < 4; ++j) h[j] = (f16)acc[ni][mi][j];
            *reinterpret_cast<f16x4*>(
                buf + feat * 256 + ((node0 * 2) ^ ((feat & 15) << 4))) = h;
        }
    __syncthreads();

    // ======== phase5: Y^T = U^T @ P^T (per batch), y=relu(+b2), v=y.wl ========
    {
        f16x8 pb[4][2];
        #pragma unroll
        for (int bb = 0; bb < 4; ++bb)
            #pragma unroll
            for (int ni = 0; ni < 2; ++ni)
                pb[bb][ni] = *reinterpret_cast<const f16x8*>(
                    Pf + bb * 1280 + (ni * 16 + lr) * 40 + gq * 8);
        float vacc[4][2];
        #pragma unroll
        for (int bb = 0; bb < 4; ++bb)
            #pragma unroll
            for (int ni = 0; ni < 2; ++ni) vacc[bb][ni] = 0.f;
        #pragma unroll
        for (int mi = 0; mi < 4; ++mi) {
            const int featb = wv * 64 + mi * 16;
            float b2v[4], wlv[4];
            #pragma unroll
            for (int j = 0; j < 4; ++j) {
                b2v[j] = b2l[featb + gq * 4 + j];
                wlv[j] = wll[featb + gq * 4 + j];
            }
            f16x8 au[4];
            #pragma unroll
            for (int bb = 0; bb < 4; ++bb) {
                const int feat = featb + lr;
                au[bb] = *reinterpret_cast<const f16x8*>(
                    buf + feat * 256 + ((bb * 64 + gq * 16) ^ ((feat & 15) << 4)));
            }
            #pragma unroll
            for (int bb = 0; bb < 4; ++bb)
                #pragma unroll
                for (int ni = 0; ni < 2; ++ni) {
                    f32x4 d = {0.f,0.f,0.f,0.f};
                    d = __builtin_amdgcn_mfma_f32_16x16x32_f16(au[bb], pb[bb][ni], d, 0, 0, 0);
                    #pragma unroll
                    for (int j = 0; j < 4; ++j) {
                        float y = fmaxf(d[j] + b2v[j], 0.f);
                        vacc[bb][ni] = fmaf(y, wlv[j], vacc[bb][ni]);
                    }
                }
        }
        #pragma unroll
        for (int bb = 0; bb < 4; ++bb)
            #pragma unroll
            for (int ni = 0; ni < 2; ++ni) {
                float v = vacc[bb][ni];
                v += __shfl_xor(v, 16);
                v += __shfl_xor(v, 32);
                if (lane < 16) red[wv * 128 + bb * 32 + ni * 16 + lr] = v;
            }
    }
    __syncthreads();
    if (tid < 128) {
        float s = 0.f;
        #pragma unroll
        for (int w = 0; w < 8; ++w) s += red[w * 128 + tid];
        vl[tid] = s;
    }
    __syncthreads();
    if (tid < 120) {
        const int bb = tid / 30, n = tid - bb * 30;
        const float* Pr = Pws + ((long)blk * 4 + bb) * 900 + n * 30;
        float z = bl[0];
        #pragma unroll
        for (int j = 0; j < 30; ++j) z = fmaf(Pr[j], vl[bb * 32 + j], z);
        zl[tid] = fmaxf(z, 0.f);
    }
    __syncthreads();
    if (tid < 16) {
        const int bb = tid >> 2, cc = tid & 3;
        float o = bc[cc];
        #pragma unroll
        for (int n = 0; n < 30; ++n) o = fmaf(zl[bb * 30 + n], wc[cc * 30 + n], o);
        out[((long)blk * 4 + bb) * 4 + cc] = o;
    }
}

extern "C" void kernel_launch(void* const* d_in, const int* in_sizes, int n_in,
                              void* d_out, int out_size, void* d_ws, size_t ws_size,
                              hipStream_t stream) {
    const float* real  = (const float*)d_in[0];
    const float* graph = (const float*)d_in[2];
    const float* W1    = (const float*)d_in[3];
    const float* b1    = (const float*)d_in[4];
    const float* W2    = (const float*)d_in[5];
    const float* b2    = (const float*)d_in[6];
    const float* Wl    = (const float*)d_in[7];
    const float* bl    = (const float*)d_in[8];
    const float* Wc    = (const float*)d_in[9];
    const float* bc    = (const float*)d_in[10];
    float* out = (float*)d_out;
    char*  ws  = (char*)d_ws;

    float* Pws = (float*)(ws + P_OFF);
    f16*   w1t = (f16*)(ws + W1T_OFF);
    f16*   w2t = (f16*)(ws + W2T_OFF);

    k_prep<<<192, 256, 0, stream>>>(W1, W2, w1t, w2t);
    (void)hipFuncSetAttribute((const void*)k_main,
                              hipFuncAttributeMaxDynamicSharedMemorySize, SMEM_BYTES);
    k_main<<<1024, 512, SMEM_BYTES, stream>>>(real, w1t, w2t, b1, b2, Wl, bl, Wc, bc,
                                              graph, Pws, out);
}

// Round 12
// 169.098 us; speedup vs baseline: 1.4981x; 1.0197x over previous
//
#include <hip/hip_runtime.h>
#include <hip/hip_bf16.h>

typedef _Float16 f16;
typedef _Float16 f16x8 __attribute__((ext_vector_type(8)));
typedef _Float16 f16x4 __attribute__((ext_vector_type(4)));
typedef float f32x4 __attribute__((ext_vector_type(4)));

#define LGKM_FENCE() do { \
    asm volatile("s_waitcnt lgkmcnt(0)" ::: "memory"); \
    __builtin_amdgcn_sched_barrier(0); \
} while (0)

// ---------------- ws layout (bytes) ----------------
#define W1T_OFF 14745600
#define W2T_OFF 15007744

// ---------------- k_prep: tiled transpose + f32->f16 (coalesced both sides) ----
// 96 blocks: 0-31 -> W1 (256x512, 4x8 tiles of 64x64); 32-95 -> W2 (512x512, 8x8).
__global__ __launch_bounds__(256) void k_prep(const float* __restrict__ W1,
                                              const float* __restrict__ W2,
                                              f16* __restrict__ w1t,
                                              f16* __restrict__ w2t) {
    __shared__ float tl[64 * 65];
    const int tid = threadIdx.x;
    int b = blockIdx.x;
    const float* src; f16* dst; int K, tk, tf;
    if (b < 32) { src = W1; dst = w1t; K = 256; tk = b >> 3; tf = b & 7; }
    else { b -= 32; src = W2; dst = w2t; K = 512; tk = b >> 3; tf = b & 7; }
    #pragma unroll
    for (int i = 0; i < 16; ++i) {
        int lin = i * 256 + tid;
        int kk = lin >> 6, ff = lin & 63;
        tl[kk * 65 + ff] = src[(long)(tk * 64 + kk) * 512 + tf * 64 + ff];
    }
    __syncthreads();
    #pragma unroll
    for (int i = 0; i < 16; ++i) {
        int lin = i * 256 + tid;
        int ff = lin >> 6, kk = lin & 63;
        dst[(long)(tf * 64 + ff) * K + tk * 64 + kk] = (f16)tl[kk * 65 + ff];
    }
}

// ---------------- k_main ----------------
// block = 4 batches (rows q*32+0..29 valid, q*32+{30,31} zeroed), M=128.
// 512 threads = 8 waves; wave owns 64 feature-cols.
// Staging fork: waves 0-3 build P (one batch each, intra-wave, fence-ordered);
// waves 4-7 stage As[128][256] f16 (R9's 2-way seg layout, two 64-row passes).
// buf alias: As 64K | P-scratch 64K..96K -> xl[128][512] 128K -> ut[512][128] 128K
#define SMEM_BYTES 152576
#define PF_OFF   131072  // Pf [4][32][40] f16 = 10240
#define B1L_OFF  141312  // [512] f32
#define B2L_OFF  143360  // [512] f32
#define WLL_OFF  145408  // [512] f32
#define RED_OFF  147456  // [8][128] f32 = 4096
#define VL_OFF   151552  // [128] f32
#define ZL_OFF   152064  // [128] f32

__global__ __launch_bounds__(512, 2) void k_main(
    const float* __restrict__ real, const f16* __restrict__ w1t,
    const f16* __restrict__ w2t, const float* __restrict__ b1,
    const float* __restrict__ b2, const float* __restrict__ wl,
    const float* __restrict__ bl, const float* __restrict__ wc,
    const float* __restrict__ bc, const float* __restrict__ graph,
    float* __restrict__ out) {
    extern __shared__ char smem[];
    char*  buf = smem;
    f16*   Pf  = (f16*)(smem + PF_OFF);
    float* b1l = (float*)(smem + B1L_OFF);
    float* b2l = (float*)(smem + B2L_OFF);
    float* wll = (float*)(smem + WLL_OFF);
    float* red = (float*)(smem + RED_OFF);
    float* vl  = (float*)(smem + VL_OFF);
    float* zl  = (float*)(smem + ZL_OFF);

    const int tid  = threadIdx.x;
    const int lane = tid & 63;
    const int wv   = tid >> 6;
    const int gq   = lane >> 4;
    const int lr   = lane & 15;
    const int blk  = blockIdx.x;         // 0..1023
    const long r0  = (long)blk * 120;

    b1l[tid] = b1[tid];
    b2l[tid] = b2[tid];
    wll[tid] = wl[tid];

    if (wv >= 4) {
        // ---- waves 4-7: stage As[128][256] f16, (row&7)<<4 swz, 2-way layout ----
        const int t   = tid & 255;                  // 0..255
        const int seg = t & 3;                      // 64-float segment
        #pragma unroll
        for (int pass = 0; pass < 2; ++pass) {
            const int srow = pass * 64 + (t >> 2);  // 0..127
            const int rr   = srow & 31;
            const bool valid = rr < 30;
            const float* p = real + (r0 + (long)(srow >> 5) * 30 + rr) * 256 + seg * 64;
            #pragma unroll
            for (int q = 0; q < 8; ++q) {
                f32x4 v0 = {0.f,0.f,0.f,0.f}, v1 = {0.f,0.f,0.f,0.f};
                if (valid) {
                    v0 = *reinterpret_cast<const f32x4*>(p + q * 8);
                    v1 = *reinterpret_cast<const f32x4*>(p + q * 8 + 4);
                }
                f16x8 h;
                h[0]=(f16)v0[0]; h[1]=(f16)v0[1]; h[2]=(f16)v0[2]; h[3]=(f16)v0[3];
                h[4]=(f16)v1[0]; h[5]=(f16)v1[1]; h[6]=(f16)v1[2]; h[7]=(f16)v1[3];
                *reinterpret_cast<f16x8*>(
                    buf + srow * 512 + ((seg * 128 + q * 16) ^ ((srow & 7) << 4))) = h;
            }
        }
    } else {
        // ---- waves 0-3: build P for batch blk*4+wv (intra-wave, fences) ----
        char*  sc   = buf + 65536 + wv * 8192;      // 8KB scratch per wave
        float* Mt   = (float*)sc;                   // [30][33] padded
        float* dinv = (float*)(sc + 3968);          // [32]
        f16*   qh   = (f16*)(sc + 4096);            // [32][32] col-major
        f16*   ql   = (f16*)(sc + 6144);
        const long b = (long)blk * 4 + wv;
        const float* g = graph + b * 4500;

        #pragma unroll
        for (int rep = 0; rep < 15; ++rep) {
            int e = rep * 64 + lane;
            if (e < 900) {
                float s = g[e] + g[900 + e] + g[1800 + e] + g[2700 + e] + g[3600 + e];
                int r = e / 30, c = e - r * 30;
                Mt[r * 33 + c] = ((s != 0.f) ? 1.f : 0.f) + ((r == c) ? 1.f : 0.f);
            }
        }
        LGKM_FENCE();
        if (lane < 30) {
            float d = 0.f;
            #pragma unroll
            for (int r = 0; r < 30; ++r) d += Mt[r * 33 + lane];
            dinv[lane] = 1.0f / sqrtf(d);
        }
        LGKM_FENCE();

        auto Sval = [&](int i, int j) -> float {
            if (i >= 30 || j >= 30) return 0.f;
            return dinv[i] * Mt[j * 33 + i] * dinv[j];
        };

        f16x8 sh[2], sl[2];
        #pragma unroll
        for (int mi = 0; mi < 2; ++mi)
            #pragma unroll
            for (int jj = 0; jj < 8; ++jj) {
                float v = Sval(mi * 16 + lr, gq * 8 + jj);
                f16 h = (f16)v;
                sh[mi][jj] = h;
                sl[mi][jj] = (f16)(v - (float)h);
            }

        f32x4 qd[2][2], racc[2][2];
        #pragma unroll
        for (int mi = 0; mi < 2; ++mi)
            #pragma unroll
            for (int ni = 0; ni < 2; ++ni)
                #pragma unroll
                for (int r = 0; r < 4; ++r) {
                    int row = mi * 16 + gq * 4 + r, col = ni * 16 + lr;
                    qd[mi][ni][r] = Sval(row, col);
                    racc[mi][ni][r] = (row == col) ? 0.1f : 0.f;
                }

        float c = 0.1f;
        for (int k = 1; k <= 9; ++k) {
            c *= 0.9f;
            #pragma unroll
            for (int mi = 0; mi < 2; ++mi)
                #pragma unroll
                for (int ni = 0; ni < 2; ++ni) {
                    racc[mi][ni] += c * qd[mi][ni];
                    f16x4 hh, ll;
                    #pragma unroll
                    for (int r = 0; r < 4; ++r) {
                        float v = qd[mi][ni][r];
                        f16 h = (f16)v;
                        hh[r] = h;
                        ll[r] = (f16)(v - (float)h);
                    }
                    const int col = ni * 16 + lr, rowb = mi * 16 + gq * 4;
                    *reinterpret_cast<f16x4*>(qh + col * 32 + rowb) = hh;
                    *reinterpret_cast<f16x4*>(ql + col * 32 + rowb) = ll;
                }
            LGKM_FENCE();
            f16x8 bh[2], bl2[2];
            #pragma unroll
            for (int ni = 0; ni < 2; ++ni) {
                const int col = ni * 16 + lr;
                bh[ni]  = *reinterpret_cast<const f16x8*>(qh + col * 32 + gq * 8);
                bl2[ni] = *reinterpret_cast<const f16x8*>(ql + col * 32 + gq * 8);
            }
            #pragma unroll
            for (int mi = 0; mi < 2; ++mi)
                #pragma unroll
                for (int ni = 0; ni < 2; ++ni) {
                    f32x4 d = {0.f, 0.f, 0.f, 0.f};
                    d = __builtin_amdgcn_mfma_f32_16x16x32_f16(sh[mi], bh[ni],  d, 0, 0, 0);
                    d = __builtin_amdgcn_mfma_f32_16x16x32_f16(sh[mi], bl2[ni], d, 0, 0, 0);
                    d = __builtin_amdgcn_mfma_f32_16x16x32_f16(sl[mi], bh[ni],  d, 0, 0, 0);
                    qd[mi][ni] = d;
                }
        }
        const float cf = 0.3486784401f;   // 0.9^10
        #pragma unroll
        for (int mi = 0; mi < 2; ++mi)
            #pragma unroll
            for (int ni = 0; ni < 2; ++ni)
                #pragma unroll
                for (int r = 0; r < 4; ++r) {
                    int row = mi * 16 + gq * 4 + r, col = ni * 16 + lr;
                    float val = racc[mi][ni][r] + cf * qd[mi][ni][r];
                    bool in = (row < 30 && col < 30);
                    Pf[wv * 1280 + row * 40 + col] = (f16)(in ? val : 0.f);
                }
    }

    f32x4 acc[4][8];
    #pragma unroll
    for (int a = 0; a < 4; ++a)
        #pragma unroll
        for (int b = 0; b < 8; ++b) { f32x4 z = {0.f,0.f,0.f,0.f}; acc[a][b] = z; }
    __syncthreads();                      // As + Pf visible

    // ======== GEMM1: D[feat][node] = W1^T @ A^T, K=256 — barrier-free ========
    const f16* w1p = w1t + (wv * 64 + lr) * 256;
    {
        f16x8 waA[4], waB[4];
        #pragma unroll
        for (int mi = 0; mi < 4; ++mi) {
            waA[mi] = *reinterpret_cast<const f16x8*>(w1p + mi * 4096 + gq * 8);
            waB[mi] = *reinterpret_cast<const f16x8*>(w1p + mi * 4096 + 32 + gq * 8);
        }
        #pragma unroll
        for (int kc2 = 0; kc2 < 4; ++kc2) {
            #pragma unroll
            for (int half = 0; half < 2; ++half) {
                const int kc = 2 * kc2 + half;
                f16x8 bf[8];
                #pragma unroll
                for (int ni = 0; ni < 8; ++ni) {
                    const int row = ni * 16 + lr;
                    bf[ni] = *reinterpret_cast<const f16x8*>(
                        buf + row * 512 + ((kc * 64 + gq * 16) ^ ((row & 7) << 4)));
                }
                __builtin_amdgcn_s_setprio(1);
                #pragma unroll
                for (int mi = 0; mi < 4; ++mi)
                    #pragma unroll
                    for (int ni = 0; ni < 8; ++ni)
                        acc[mi][ni] = __builtin_amdgcn_mfma_f32_16x16x32_f16(
                            half ? waB[mi] : waA[mi], bf[ni], acc[mi][ni], 0, 0, 0);
                __builtin_amdgcn_s_setprio(0);
                if (kc + 2 < 8) {
                    #pragma unroll
                    for (int mi = 0; mi < 4; ++mi) {
                        f16x8 w = *reinterpret_cast<const f16x8*>(
                            w1p + mi * 4096 + (kc + 2) * 32 + gq * 8);
                        if (half) waB[mi] = w; else waA[mi] = w;
                    }
                }
            }
        }
    }
    __syncthreads();   // As reads done; buf -> xl[128][512] f16

    // ---- ep1: xl[node][feat] = relu(acc + b1), b64 writes, (node&15)<<4 swz ----
    #pragma unroll
    for (int mi = 0; mi < 4; ++mi) {
        const int featb = wv * 64 + mi * 16 + gq * 4;
        float b1v[4];
        #pragma unroll
        for (int j = 0; j < 4; ++j) b1v[j] = b1l[featb + j];
        #pragma unroll
        for (int ni = 0; ni < 8; ++ni) {
            const int node = ni * 16 + lr;
            f16x4 h;
            #pragma unroll
            for (int j = 0; j < 4; ++j)
                h[j] = (f16)fmaxf(acc[mi][ni][j] + b1v[j], 0.f);
            *reinterpret_cast<f16x4*>(
                buf + node * 1024 + ((featb * 2) ^ ((node & 15) << 4))) = h;
        }
    }
    #pragma unroll
    for (int a = 0; a < 4; ++a)
        #pragma unroll
        for (int b = 0; b < 8; ++b) { f32x4 z = {0.f,0.f,0.f,0.f}; acc[a][b] = z; }
    __syncthreads();

    // ======== GEMM2: D[node][feat] = x @ W2, K=512 — barrier-free ========
    const f16* w2p = w2t + (wv * 64 + lr) * 512;
    {
        f16x8 bfA[4], bfB[4];
        #pragma unroll
        for (int ni = 0; ni < 4; ++ni) {
            bfA[ni] = *reinterpret_cast<const f16x8*>(w2p + ni * 8192 + gq * 8);
            bfB[ni] = *reinterpret_cast<const f16x8*>(w2p + ni * 8192 + 32 + gq * 8);
        }
        #pragma unroll
        for (int kc2 = 0; kc2 < 8; ++kc2) {
            #pragma unroll
            for (int half = 0; half < 2; ++half) {
                const int kc = 2 * kc2 + half;
                f16x8 af[8];
                #pragma unroll
                for (int mi = 0; mi < 8; ++mi) {
                    const int row = mi * 16 + lr;
                    af[mi] = *reinterpret_cast<const f16x8*>(
                        buf + row * 1024 + (((kc * 32 + gq * 8) * 2) ^ ((row & 15) << 4)));
                }
                __builtin_amdgcn_s_setprio(1);
                #pragma unroll
                for (int mi = 0; mi < 8; ++mi)
                    #pragma unroll
                    for (int ni = 0; ni < 4; ++ni)
                        acc[ni][mi] = __builtin_amdgcn_mfma_f32_16x16x32_f16(
                            af[mi], half ? bfB[ni] : bfA[ni], acc[ni][mi], 0, 0, 0);
                __builtin_amdgcn_s_setprio(0);
                if (kc + 2 < 16) {
                    #pragma unroll
                    for (int ni = 0; ni < 4; ++ni) {
                        f16x8 w = *reinterpret_cast<const f16x8*>(
                            w2p + ni * 8192 + (kc + 2) * 32 + gq * 8);
                        if (half) bfB[ni] = w; else bfA[ni] = w;
                    }
                }
            }
        }
    }
    __syncthreads();   // xl reads done; buf -> ut[512][128]

    // ---- ep2: ut[feat][node], b64 writes, (feat&15)<<4 swizzle ----
    #pragma unroll
    for (int mi = 0; mi < 8; ++mi)
        #pragma unroll
        for (int ni = 0; ni < 4; ++ni) {
            const int feat  = wv * 64 + ni * 16 + lr;
            const int node0 = mi * 16 + gq * 4;
            f16x4 h;
            #pragma unroll
            for (int j = 0; j < 4; ++j) h[j] = (f16)acc[ni][mi][j];
            *reinterpret_cast<f16x4*>(
                buf + feat * 256 + ((node0 * 2) ^ ((feat & 15) << 4))) = h;
        }
    __syncthreads();

    // ======== phase5: Y^T = U^T @ P^T (per batch), y=relu(+b2), v=y.wl ========
    {
        f16x8 pb[4][2];
        #pragma unroll
        for (int bb = 0; bb < 4; ++bb)
            #pragma unroll
            for (int ni = 0; ni < 2; ++ni)
                pb[bb][ni] = *reinterpret_cast<const f16x8*>(
                    Pf + bb * 1280 + (ni * 16 + lr) * 40 + gq * 8);
        float vacc[4][2];
        #pragma unroll
        for (int bb = 0; bb < 4; ++bb)
            #pragma unroll
            for (int ni = 0; ni < 2; ++ni) vacc[bb][ni] = 0.f;
        #pragma unroll
        for (int mi = 0; mi < 4; ++mi) {
            const int featb = wv * 64 + mi * 16;
            float b2v[4], wlv[4];
            #pragma unroll
            for (int j = 0; j < 4; ++j) {
                b2v[j] = b2l[featb + gq * 4 + j];
                wlv[j] = wll[featb + gq * 4 + j];
            }
            f16x8 au[4];
            #pragma unroll
            for (int bb = 0; bb < 4; ++bb) {
                const int feat = featb + lr;
                au[bb] = *reinterpret_cast<const f16x8*>(
                    buf + feat * 256 + ((bb * 64 + gq * 16) ^ ((feat & 15) << 4)));
            }
            #pragma unroll
            for (int bb = 0; bb < 4; ++bb)
                #pragma unroll
                for (int ni = 0; ni < 2; ++ni) {
                    f32x4 d = {0.f,0.f,0.f,0.f};
                    d = __builtin_amdgcn_mfma_f32_16x16x32_f16(au[bb], pb[bb][ni], d, 0, 0, 0);
                    #pragma unroll
                    for (int j = 0; j < 4; ++j) {
                        float y = fmaxf(d[j] + b2v[j], 0.f);
                        vacc[bb][ni] = fmaf(y, wlv[j], vacc[bb][ni]);
                    }
                }
        }
        #pragma unroll
        for (int bb = 0; bb < 4; ++bb)
            #pragma unroll
            for (int ni = 0; ni < 2; ++ni) {
                float v = vacc[bb][ni];
                v += __shfl_xor(v, 16);
                v += __shfl_xor(v, 32);
                if (lane < 16) red[wv * 128 + bb * 32 + ni * 16 + lr] = v;
            }
    }
    __syncthreads();
    if (tid < 128) {
        float s = 0.f;
        #pragma unroll
        for (int w = 0; w < 8; ++w) s += red[w * 128 + tid];
        vl[tid] = s;
    }
    __syncthreads();
    if (tid < 120) {
        const int bb = tid / 30, n = tid - bb * 30;
        const f16* Pr = Pf + bb * 1280 + n * 40;
        float z = bl[0];
        #pragma unroll
        for (int j = 0; j < 30; ++j) z = fmaf((float)Pr[j], vl[bb * 32 + j], z);
        zl[tid] = fmaxf(z, 0.f);
    }
    __syncthreads();
    if (tid < 16) {
        const int bb = tid >> 2, cc = tid & 3;
        float o = bc[cc];
        #pragma unroll
        for (int n = 0; n < 30; ++n) o = fmaf(zl[bb * 30 + n], wc[cc * 30 + n], o);
        out[((long)blk * 4 + bb) * 4 + cc] = o;
    }
}

extern "C" void kernel_launch(void* const* d_in, const int* in_sizes, int n_in,
                              void* d_out, int out_size, void* d_ws, size_t ws_size,
                              hipStream_t stream) {
    const float* real  = (const float*)d_in[0];
    const float* graph = (const float*)d_in[2];
    const float* W1    = (const float*)d_in[3];
    const float* b1    = (const float*)d_in[4];
    const float* W2    = (const float*)d_in[5];
    const float* b2    = (const float*)d_in[6];
    const float* Wl    = (const float*)d_in[7];
    const float* bl    = (const float*)d_in[8];
    const float* Wc    = (const float*)d_in[9];
    const float* bc    = (const float*)d_in[10];
    float* out = (float*)d_out;
    char*  ws  = (char*)d_ws;

    f16* w1t = (f16*)(ws + W1T_OFF);
    f16* w2t = (f16*)(ws + W2T_OFF);

    k_prep<<<96, 256, 0, stream>>>(W1, W2, w1t, w2t);
    (void)hipFuncSetAttribute((const void*)k_main,
                              hipFuncAttributeMaxDynamicSharedMemorySize, SMEM_BYTES);
    k_main<<<1024, 512, SMEM_BYTES, stream>>>(real, w1t, w2t, b1, b2, Wl, bl, Wc, bc,
                                              graph, out);
}